// Round 4
// baseline (1376.543 us; speedup 1.0000x reference)
//
#include <hip/hip_runtime.h>

// ---------------------------------------------------------------------------
// 6-layer GCN. Per layer: h = lrelu?(x) @ W ; agg = D^-1/2 (A+I) D^-1/2 h + b
// R3: XCD-pinned feature-sliced aggregation.
//   h/agg live in slice-major layout hS[8][N][8]; slice s is processed by
//   blocks with blockIdx&7==s (round-robin block->XCD dispatch => slice s is
//   L2-resident in XCD s: 3.2 MB < 4 MiB). Gathers become L2 hits.
// d_ws layout: rowptr[N+1] | dinv[N] | ssrc[E] | bufA[64N] | bufB[64N]
// Build temps alias into bufA (released before layer 0 writes bufA).
// ---------------------------------------------------------------------------

__device__ __forceinline__ float readlane_f(float v, int l) {
    union { float f; int i; } u;
    u.f = v;
    u.i = __builtin_amdgcn_readlane(u.i, l);
    return u.f;
}

// --- pass 1: coarse histogram of dst>>7 into NB buckets ---------------------
__global__ __launch_bounds__(256) void bucket_hist(const int* __restrict__ dst,
                                                   int* __restrict__ ghist,
                                                   int E, int NB) {
    __shared__ int h[1024];
    for (int i = threadIdx.x; i < NB; i += 256) h[i] = 0;
    __syncthreads();
    int i = blockIdx.x * blockDim.x + threadIdx.x;
    int stride = gridDim.x * blockDim.x;
    for (; i < E; i += stride) atomicAdd(&h[dst[i] >> 7], 1);
    __syncthreads();
    for (int j = threadIdx.x; j < NB; j += 256) {
        int c = h[j];
        if (c) atomicAdd(&ghist[j], c);
    }
}

// --- pass 2: exclusive scan of bucket counts (single block, 1024 thr) -------
__global__ void bucket_scan(const int* __restrict__ ghist, int* __restrict__ base,
                            int* __restrict__ cursor, int NB, int E) {
    int tid = threadIdx.x, lane = tid & 63, wid = tid >> 6;
    int v = (tid < NB) ? ghist[tid] : 0;
    int incl = v;
#pragma unroll
    for (int off = 1; off < 64; off <<= 1) {
        int t = __shfl_up(incl, off);
        if (lane >= off) incl += t;
    }
    __shared__ int ws[16];
    if (lane == 63) ws[wid] = incl;
    __syncthreads();
    if (tid == 0) {
        int run = 0;
        for (int i = 0; i < 16; ++i) { int t = ws[i]; ws[i] = run; run += t; }
    }
    __syncthreads();
    int excl = ws[wid] + incl - v;
    if (tid < NB) { base[tid] = excl; cursor[tid] = excl; }
    if (tid == 0) base[NB] = E;
}

// --- pass 3: scatter edges into bucket-sorted (bsrc, bdl) -------------------
__global__ __launch_bounds__(256) void bucket_scatter(
    const int* __restrict__ src, const int* __restrict__ dst,
    int* __restrict__ cursor, int* __restrict__ bsrc,
    unsigned char* __restrict__ bdl, int E, int NB) {
    __shared__ int h[1024];
    __shared__ int rb[1024];
    const int CH = 4096;
    for (int c0 = blockIdx.x * CH; c0 < E; c0 += gridDim.x * CH) {
        int cend = c0 + CH < E ? c0 + CH : E;
        for (int j = threadIdx.x; j < NB; j += 256) h[j] = 0;
        __syncthreads();
        for (int i = c0 + threadIdx.x; i < cend; i += 256)
            atomicAdd(&h[dst[i] >> 7], 1);
        __syncthreads();
        for (int j = threadIdx.x; j < NB; j += 256) {
            int c = h[j];
            rb[j] = c ? atomicAdd(&cursor[j], c) : 0;
            h[j] = 0;
        }
        __syncthreads();
        for (int i = c0 + threadIdx.x; i < cend; i += 256) {
            int d = dst[i];
            int b = d >> 7;
            int p = rb[b] + atomicAdd(&h[b], 1);
            bsrc[p] = src[i];
            bdl[p] = (unsigned char)(d & 127);
        }
        __syncthreads();
    }
}

// --- pass 4: per-bucket CSR finalize: rowptr, dinv, ssrc --------------------
__global__ __launch_bounds__(256) void bucket_finalize(
    const int* __restrict__ base, const int* __restrict__ bsrc,
    const unsigned char* __restrict__ bdl, int* __restrict__ rowptr,
    int* __restrict__ ssrc, float* __restrict__ dinv, int N, int NB, int E) {
    __shared__ int cnt[128];
    __shared__ int cur[128];
    __shared__ int w0sum;
    const int tid = threadIdx.x;
    const int lane = tid & 63;
    for (int b = blockIdx.x; b < NB; b += gridDim.x) {
        const int s = base[b], e = base[b + 1];
        const int d0 = b << 7;
        const int w = (N - d0 < 128) ? (N - d0) : 128;
        if (tid < 128) cnt[tid] = 0;
        __syncthreads();
        for (int i = s + tid; i < e; i += 256) atomicAdd(&cnt[bdl[i]], 1);
        __syncthreads();
        int v = (tid < 128) ? cnt[tid] : 0;
        int incl = v;
#pragma unroll
        for (int off = 1; off < 64; off <<= 1) {
            int t = __shfl_up(incl, off);
            if (lane >= off) incl += t;
        }
        if (tid == 63) w0sum = incl;
        __syncthreads();
        int excl = incl - v + ((tid >= 64 && tid < 128) ? w0sum : 0);
        if (tid < 128) cur[tid] = s + excl;
        if (tid < w) {
            rowptr[d0 + tid] = s + excl;
            dinv[d0 + tid] = rsqrtf((float)(v + 1));   // +1 self loop
        }
        __syncthreads();
        for (int i = s + tid; i < e; i += 256) {
            int p = atomicAdd(&cur[bdl[i]], 1);
            ssrc[p] = bsrc[i];
        }
        __syncthreads();
    }
    if (blockIdx.x == 0 && tid == 0) rowptr[N] = E;
}

// --- dense transform: hS[l>>3][row*8+(l&7)] = sum_k lrelu?(x[row,k])*W[k,l] -
// IN_SLICED: x is slice-major [8][n][8]; else row-major [n][K].
template <int K, bool LRELU, bool IN_SLICED>
__global__ __launch_bounds__(256) void gemm_h(
    const float* __restrict__ x, const float* __restrict__ W,
    float* __restrict__ hS, int n) {
    const int lane = threadIdx.x & 63;
    const int gw = blockIdx.x * (blockDim.x >> 6) + (threadIdx.x >> 6);
    const int nw = gridDim.x * (blockDim.x >> 6);
    const int sl = lane >> 3, f8 = lane & 7;
    const int slot = sl * n * 8 + f8;   // slice-major offset for this lane

    float wreg[K];
#pragma unroll
    for (int k = 0; k < K; ++k) wreg[k] = W[k * 64 + lane];

    for (int row = gw; row < n; row += nw) {
        float xv0, xv1 = 0.f;
        if (IN_SLICED) {
            xv0 = __builtin_nontemporal_load(x + (size_t)slot + (size_t)row * 8);
        } else {
            xv0 = __builtin_nontemporal_load(x + (size_t)row * K + lane);
            if (K == 128)
                xv1 = __builtin_nontemporal_load(x + (size_t)row * K + 64 + lane);
        }
        if (LRELU) xv0 = xv0 >= 0.f ? xv0 : 0.2f * xv0;
        float a0 = 0.f, a1 = 0.f, a2 = 0.f, a3 = 0.f;
#pragma unroll
        for (int k = 0; k < 64; k += 4) {
            a0 = fmaf(readlane_f(xv0, k + 0), wreg[k + 0], a0);
            a1 = fmaf(readlane_f(xv0, k + 1), wreg[k + 1], a1);
            a2 = fmaf(readlane_f(xv0, k + 2), wreg[k + 2], a2);
            a3 = fmaf(readlane_f(xv0, k + 3), wreg[k + 3], a3);
        }
        if (K == 128) {
#pragma unroll
            for (int k = 0; k < 64; k += 4) {
                a0 = fmaf(readlane_f(xv1, k + 0), wreg[64 + k + 0], a0);
                a1 = fmaf(readlane_f(xv1, k + 1), wreg[64 + k + 1], a1);
                a2 = fmaf(readlane_f(xv1, k + 2), wreg[64 + k + 2], a2);
                a3 = fmaf(readlane_f(xv1, k + 3), wreg[64 + k + 3], a3);
            }
        }
        float acc = (a0 + a1) + (a2 + a3);
        __builtin_nontemporal_store(acc, hS + (size_t)slot + (size_t)row * 8);
    }
}

// --- sliced CSR aggregation: slice = blockIdx&7 (pinned to one XCD),
//     8 lanes per dst row (lane&7 = feature), 32 rows per block step. --------
__global__ __launch_bounds__(256) void csr_agg_sliced(
    const float* __restrict__ hS, const int* __restrict__ rowptr,
    const int* __restrict__ ssrc, const float* __restrict__ dinv,
    const float* __restrict__ b, float* __restrict__ aggS, int N) {
    const int s = blockIdx.x & 7;
    const int cb = blockIdx.x >> 3;
    const int nchunk = gridDim.x >> 3;
    const int g = threadIdx.x >> 3;   // 0..31
    const int f = threadIdx.x & 7;
    const float* __restrict__ h = hS + (size_t)s * N * 8;
    float* __restrict__ agg = aggS + (size_t)s * N * 8;
    const float bf = b[s * 8 + f];

    for (int d = cb * 32 + g; d < N; d += nchunk * 32) {
        const float di = dinv[d];
        float acc = fmaf(di * di, h[d * 8 + f], bf);
        int e = rowptr[d];
        const int end = rowptr[d + 1];
        for (; e + 4 <= end; e += 4) {
            int s0 = __builtin_nontemporal_load(ssrc + e);
            int s1 = __builtin_nontemporal_load(ssrc + e + 1);
            int s2 = __builtin_nontemporal_load(ssrc + e + 2);
            int s3 = __builtin_nontemporal_load(ssrc + e + 3);
            float n0 = di * dinv[s0], n1 = di * dinv[s1];
            float n2 = di * dinv[s2], n3 = di * dinv[s3];
            float v0 = h[s0 * 8 + f], v1 = h[s1 * 8 + f];
            float v2 = h[s2 * 8 + f], v3 = h[s3 * 8 + f];
            acc = fmaf(v0, n0, acc);
            acc = fmaf(v1, n1, acc);
            acc = fmaf(v2, n2, acc);
            acc = fmaf(v3, n3, acc);
        }
        for (; e < end; ++e) {
            int s0 = __builtin_nontemporal_load(ssrc + e);
            acc = fmaf(h[s0 * 8 + f], di * dinv[s0], acc);
        }
        __builtin_nontemporal_store(acc, agg + d * 8 + f);
    }
}

// --- final layer: K=64 (slice-major input) -> 4, lrelu on input -------------
__global__ __launch_bounds__(256) void gemm4_h(
    const float* __restrict__ xS, const float* __restrict__ W,  // [64,4]
    float* __restrict__ h4, int n) {
    int i = blockIdx.x * blockDim.x + threadIdx.x;
    int stride = gridDim.x * blockDim.x;
    for (; i < n; i += stride) {
        float a0 = 0.f, a1 = 0.f, a2 = 0.f, a3 = 0.f;
#pragma unroll
        for (int s = 0; s < 8; ++s) {
            const float4* p = (const float4*)(xS + (size_t)s * n * 8 + (size_t)i * 8);
            float4 u = p[0], v = p[1];
            float e0 = u.x >= 0.f ? u.x : 0.2f * u.x;
            float e1 = u.y >= 0.f ? u.y : 0.2f * u.y;
            float e2 = u.z >= 0.f ? u.z : 0.2f * u.z;
            float e3 = u.w >= 0.f ? u.w : 0.2f * u.w;
            float e4 = v.x >= 0.f ? v.x : 0.2f * v.x;
            float e5 = v.y >= 0.f ? v.y : 0.2f * v.y;
            float e6 = v.z >= 0.f ? v.z : 0.2f * v.z;
            float e7 = v.w >= 0.f ? v.w : 0.2f * v.w;
            int k = s * 8;
            a0 = fmaf(e0, W[(k + 0) * 4 + 0], a0); a1 = fmaf(e0, W[(k + 0) * 4 + 1], a1);
            a2 = fmaf(e0, W[(k + 0) * 4 + 2], a2); a3 = fmaf(e0, W[(k + 0) * 4 + 3], a3);
            a0 = fmaf(e1, W[(k + 1) * 4 + 0], a0); a1 = fmaf(e1, W[(k + 1) * 4 + 1], a1);
            a2 = fmaf(e1, W[(k + 1) * 4 + 2], a2); a3 = fmaf(e1, W[(k + 1) * 4 + 3], a3);
            a0 = fmaf(e2, W[(k + 2) * 4 + 0], a0); a1 = fmaf(e2, W[(k + 2) * 4 + 1], a1);
            a2 = fmaf(e2, W[(k + 2) * 4 + 2], a2); a3 = fmaf(e2, W[(k + 2) * 4 + 3], a3);
            a0 = fmaf(e3, W[(k + 3) * 4 + 0], a0); a1 = fmaf(e3, W[(k + 3) * 4 + 1], a1);
            a2 = fmaf(e3, W[(k + 3) * 4 + 2], a2); a3 = fmaf(e3, W[(k + 3) * 4 + 3], a3);
            a0 = fmaf(e4, W[(k + 4) * 4 + 0], a0); a1 = fmaf(e4, W[(k + 4) * 4 + 1], a1);
            a2 = fmaf(e4, W[(k + 4) * 4 + 2], a2); a3 = fmaf(e4, W[(k + 4) * 4 + 3], a3);
            a0 = fmaf(e5, W[(k + 5) * 4 + 0], a0); a1 = fmaf(e5, W[(k + 5) * 4 + 1], a1);
            a2 = fmaf(e5, W[(k + 5) * 4 + 2], a2); a3 = fmaf(e5, W[(k + 5) * 4 + 3], a3);
            a0 = fmaf(e6, W[(k + 6) * 4 + 0], a0); a1 = fmaf(e6, W[(k + 6) * 4 + 1], a1);
            a2 = fmaf(e6, W[(k + 6) * 4 + 2], a2); a3 = fmaf(e6, W[(k + 6) * 4 + 3], a3);
            a0 = fmaf(e7, W[(k + 7) * 4 + 0], a0); a1 = fmaf(e7, W[(k + 7) * 4 + 1], a1);
            a2 = fmaf(e7, W[(k + 7) * 4 + 2], a2); a3 = fmaf(e7, W[(k + 7) * 4 + 3], a3);
        }
        ((float4*)h4)[i] = make_float4(a0, a1, a2, a3);
    }
}

__global__ __launch_bounds__(256) void csr_agg4(
    const float* __restrict__ h4, const int* __restrict__ rowptr,
    const int* __restrict__ ssrc, const float* __restrict__ dinv,
    const float* __restrict__ b, float* __restrict__ out, int n) {
    int i = blockIdx.x * blockDim.x + threadIdx.x;
    int stride = gridDim.x * blockDim.x;
    float b0 = b[0], b1 = b[1], b2 = b[2], b3 = b[3];
    for (; i < n; i += stride) {
        float di = dinv[i];
        float d2 = di * di;
        float4 hv = ((const float4*)h4)[i];
        float a0 = fmaf(d2, hv.x, b0), a1 = fmaf(d2, hv.y, b1);
        float a2 = fmaf(d2, hv.z, b2), a3 = fmaf(d2, hv.w, b3);
        int e = rowptr[i], end = rowptr[i + 1];
        for (; e < end; ++e) {
            int s = __builtin_nontemporal_load(ssrc + e);
            float nrm = di * dinv[s];
            float4 v = ((const float4*)h4)[s];
            a0 = fmaf(nrm, v.x, a0); a1 = fmaf(nrm, v.y, a1);
            a2 = fmaf(nrm, v.z, a2); a3 = fmaf(nrm, v.w, a3);
        }
        ((float4*)out)[i] = make_float4(a0, a1, a2, a3);
    }
}

static inline size_t al64(size_t x) { return (x + 63) & ~(size_t)63; }

extern "C" void kernel_launch(void* const* d_in, const int* in_sizes, int n_in,
                              void* d_out, int out_size, void* d_ws, size_t ws_size,
                              hipStream_t stream) {
    const float* x  = (const float*)d_in[0];
    const int* ei   = (const int*)d_in[1];
    const float* W0 = (const float*)d_in[2];
    const float* b0 = (const float*)d_in[3];
    const float* W1 = (const float*)d_in[4];
    const float* b1 = (const float*)d_in[5];
    const float* W2 = (const float*)d_in[6];
    const float* b2 = (const float*)d_in[7];
    const float* W3 = (const float*)d_in[8];
    const float* b3 = (const float*)d_in[9];
    const float* W4 = (const float*)d_in[10];
    const float* b4 = (const float*)d_in[11];
    const float* W5 = (const float*)d_in[12];
    const float* b5 = (const float*)d_in[13];

    const int N = in_sizes[0] / 128;
    const int E = in_sizes[1] / 2;
    const int* src  = ei;       // edge_index[0] = message sources
    const int* dstp = ei + E;   // edge_index[1] = aggregation targets
    const int NB = (N + 127) >> 7;   // dst buckets of 128 ids (NB <= 1024)

    float* ws = (float*)d_ws;
    size_t off = 0;
    int*   rowptr = (int*)(ws + off);   off += al64((size_t)N + 1);
    float* dinv   = ws + off;           off += al64((size_t)N);
    int*   ssrc   = (int*)(ws + off);   off += al64((size_t)E);
    float* bufA   = ws + off;           off += (size_t)64 * N;
    float* bufB   = ws + off;

    // build temps alias into bufA (released before layer 0 writes bufA)
    int* ghist = (int*)bufA;                       // [1024]
    int* bbase = ghist + 1024;                     // [NB+1]
    int* bcur  = bbase + 1088;                     // [NB]
    int* bsrc  = (int*)(bufA + 4096);              // [E]
    unsigned char* bdl = (unsigned char*)(bsrc + E);  // [E]

    // ---- graph build (bucketed counting sort) ----
    hipMemsetAsync(ghist, 0, 1024 * sizeof(int), stream);
    bucket_hist<<<391, 256, 0, stream>>>(dstp, ghist, E, NB);
    bucket_scan<<<1, 1024, 0, stream>>>(ghist, bbase, bcur, NB, E);
    bucket_scatter<<<391, 256, 0, stream>>>(src, dstp, bcur, bsrc, bdl, E, NB);
    bucket_finalize<<<NB, 256, 0, stream>>>(bbase, bsrc, bdl, rowptr, ssrc, dinv, N, NB, E);

    // ---- layer 0: x[N,128] row-major -> sliced ----
    gemm_h<128, false, false><<<2048, 256, 0, stream>>>(x, W0, bufA, N);
    csr_agg_sliced<<<2048, 256, 0, stream>>>(bufA, rowptr, ssrc, dinv, b0, bufB, N);

    // ---- layers 1-4 (sliced in, sliced out) ----
    const float* Ws[4] = {W1, W2, W3, W4};
    const float* bs[4] = {b1, b2, b3, b4};
    for (int l = 0; l < 4; ++l) {
        gemm_h<64, true, true><<<2048, 256, 0, stream>>>(bufB, Ws[l], bufA, N);
        csr_agg_sliced<<<2048, 256, 0, stream>>>(bufA, rowptr, ssrc, dinv, bs[l], bufB, N);
    }

    // ---- layer 5: sliced 64 -> 4 ----
    gemm4_h<<<1024, 256, 0, stream>>>(bufB, W5, bufA, N);
    csr_agg4<<<2048, 256, 0, stream>>>(bufA, rowptr, ssrc, dinv, b5, (float*)d_out, N);
}